// Round 8
// baseline (244.184 us; speedup 1.0000x reference)
//
#include <hip/hip_runtime.h>

#define HDIM  256
#define YP    264              // padded Y row length in bf16 elems
#define SPBM  8                // samples per block-iteration
#define MROWS (SPBM * 8)       // 64 jet rows per block

typedef unsigned short u16;
typedef __attribute__((ext_vector_type(8))) short  short8;   // 8 bf16 (4 VGPRs)
typedef __attribute__((ext_vector_type(4))) float  f32x4;    // MFMA acc

// ---------------- Wt fragment layout + column permutation (r5/r6) ---------
// B-fragment storage is lane-contiguous (1KB streaming loads per wave), and
// tile-col -> logical-n mapping is permuted:  tile t, tile-col m holds
// logical n = (t>>2)*64 + 4*m + (t&3).  So lane lm's four nt-accumulators
// are logical cols 4*lm..4*lm+3 -> epilogue writes ds_write_b64 per row.
// Row permutation (r3): physical row R for (sample s, channel c):
//   R = 32*(s>>2) + 16*(c>>2) + 4*(s&3) + (c&3)
// => per C-tile pair lane group g holds all 8 channels of sample 4h+g
// in registers -> per-lane jet epilogue, no shuffles.
// Round 8: PERSISTENT blocks — grid 1024 (= 4/CU x 256 CU exactly), each
// block runs 2 sample-group iterations.  One generation: no mid-kernel
// block-slot refills, ramp/drain paid once, iter-2 L2-warm.  xs4 staging
// and its barrier removed (x loads are wave-uniform broadcasts).
// -------------------------------------------------------------------------

// proper RNE, used once in prepass for weights
__device__ __forceinline__ u16 f2bf_rne(float f) {
    union { float f; unsigned int u; } v; v.f = f;
    unsigned int r = v.u + 0x7fffu + ((v.u >> 16) & 1u);
    return (u16)(r >> 16);
}
// pack two f32 -> bf16x2 in one VALU instr (RNE)
__device__ __forceinline__ unsigned int cvtpk(float a, float b) {
    unsigned int r;
    asm("v_cvt_pk_bf16_f32 %0, %1, %2" : "=v"(r) : "v"(a), "v"(b));
    return r;
}
// tanh(x) = 1 - 2/(e^{2x}+1) on raw v_exp_f32 / v_rcp_f32 (~4 instr, NaN-free)
__device__ __forceinline__ float fast_tanh(float x) {
    const float e = __builtin_amdgcn_exp2f(x * 2.885390081777927f); // e^{2x}
    const float r = __builtin_amdgcn_rcpf(e + 1.f);
    return 1.f - 2.f * r;
}

// ---- prepass: W[k][n] f32 -> fragment-ordered, column-permuted bf16 Wt
// ---- (W1,W2,W3), plus Wo[k][2] -> Wob[2][256] bf16 at ws + 3*65536.
// 97 blocks; block = one (ks, 4 n-tiles) slab: 32 k x 64 n.
__global__ __launch_bounds__(256)
void prep_w(const float* __restrict__ W1, const float* __restrict__ W2,
            const float* __restrict__ W3, const float* __restrict__ Wo,
            u16* __restrict__ ws) {
    const int bid = blockIdx.x;
    const int tid = threadIdx.x;
    if (bid == 96) {
#pragma unroll
        for (int oc = 0; oc < 2; ++oc)
            ws[3 * 65536 + oc * 256 + tid] = f2bf_rne(Wo[tid * 2 + oc]);
        return;
    }
    const int which = bid >> 5;          // 0..2
    const int tile  = bid & 31;          // 8 k-slabs x 4 n-slabs
    const int k0 = (tile & 7) * 32;      // ks = tile & 7
    const int n0 = (tile >> 3) * 64;
    const float* W = (which == 0) ? W1 : ((which == 1) ? W2 : W3);
    __shared__ float T[32][65];
    const int rk = tid >> 4;             // 0..15
    const int rn = (tid & 15) * 4;       // 0..60
#pragma unroll
    for (int rep = 0; rep < 2; ++rep) {
        const float4 v = *(const float4*)(W + (k0 + rep * 16 + rk) * 256 + n0 + rn);
        T[rep * 16 + rk][rn + 0] = v.x;
        T[rep * 16 + rk][rn + 1] = v.y;
        T[rep * 16 + rk][rn + 2] = v.z;
        T[rep * 16 + rk][rn + 3] = v.w;
    }
    __syncthreads();
    // fragment-ordered write: thread -> (t_local = tid>>6, lane = tid&63)
    const int tl = tid >> 6;             // 0..3  (n-tile within slab, = t&3)
    const int ln = tid & 63;             // fragment lane
    const int nn = 4 * (ln & 15) + tl;           // PERMUTED logical n - n0
    const int kb = ((ln >> 4) & 3) * 8;          // k - k0 base
    short8 o;
#pragma unroll
    for (int j = 0; j < 8; ++j)
        o[j] = (short)f2bf_rne(T[kb + j][nn]);
    const int t_glob = (n0 >> 4) + tl;           // 0..15
    *(short8*)(ws + which * 65536 + ((t_glob * 8 + (tile & 7)) * 64 + ln) * 8) = o;
}

// ---- one hidden layer: Y(LDS, 64x256 bf16 jets) @ W(256x256) -> jets, in place ----
// 4 waves: wave wv owns all 64 rows x cols wv*64..+63.  acc[4][4] = 64 regs.
// C/D: col=lane&15, row=(lane>>4)*4+reg.  A: A[m=lane&15][k=8*(lane>>4)+j].
// B-loads lane-contiguous 1KB streams; B cols permuted (see header comment).
__device__ __forceinline__ void hidden_layer_mfma(u16* __restrict__ Y,
                                                  const u16* __restrict__ Wt,
                                                  const float* __restrict__ b,
                                                  int l, int wv) {
    const int lm    = l & 15;
    const int lk8   = (l >> 4) * 8;
    const int nbase = wv * 64;
    // per-lane fragment base: t = wv*4 + nt  ->  elem off = (t*8+ks)*512 + l*8
    const u16* bsrc = Wt + (wv * 4) * 4096 + l * 8;

    f32x4 acc[4][4];
#pragma unroll
    for (int mt = 0; mt < 4; ++mt)
#pragma unroll
        for (int nt = 0; nt < 4; ++nt) acc[mt][nt] = (f32x4){0.f, 0.f, 0.f, 0.f};

#pragma unroll
    for (int ks = 0; ks < 8; ++ks) {
        const int kk = ks * 32 + lk8;
        short8 a[4], bf[4];
#pragma unroll
        for (int mt = 0; mt < 4; ++mt)
            a[mt] = *(const short8*)(Y + (mt * 16 + lm) * YP + kk);
#pragma unroll
        for (int nt = 0; nt < 4; ++nt)
            bf[nt] = *(const short8*)(bsrc + nt * 4096 + ks * 512);
#pragma unroll
        for (int mt = 0; mt < 4; ++mt)
#pragma unroll
            for (int nt = 0; nt < 4; ++nt)
                acc[mt][nt] = __builtin_amdgcn_mfma_f32_16x16x32_bf16(
                    a[mt], bf[nt], acc[mt][nt], 0, 0, 0);
    }

    // bias for logical cols nbase + 4*lm + 0..3  (one float4)
    const float4 b4 = *(const float4*)(b + nbase + 4 * lm);

    __syncthreads();   // all waves done READING Y before anyone overwrites it

    const int g = l >> 4;    // sample-in-group 0..3
#pragma unroll
    for (int half = 0; half < 2; ++half) {      // samples 4*half+g
        // pk[pr][row]: pr = nt-pair (cols 4lm+2pr, +1); rows 0..3 = ch0..3,
        // rows 4..7 = ch4..7.  All indices compile-time -> registers.
        unsigned int pk[2][8];
#pragma unroll
        for (int pr = 0; pr < 2; ++pr) {
            const int na = 2 * pr, nb = 2 * pr + 1;
            const float bba = (pr == 0) ? b4.x : b4.z;
            const float bbb = (pr == 0) ? b4.y : b4.w;
            const float ty0 = fast_tanh(acc[2 * half][na][0] + bba);
            const float ty1 = fast_tanh(acc[2 * half][nb][0] + bbb);
            const float t0 = 1.f - ty0 * ty0, t1 = 1.f - ty1 * ty1;
            const float m0 = -2.f * ty0 * t0, m1 = -2.f * ty1 * t1;
            pk[pr][0] = cvtpk(ty0, ty1);
            pk[pr][4] = cvtpk(t0 * acc[2 * half + 1][na][0],
                              t1 * acc[2 * half + 1][nb][0]);
#pragma unroll
            for (int j = 1; j < 4; ++j) {
                const float a0 = acc[2 * half][na][j];
                const float a1 = acc[2 * half][nb][j];
                pk[pr][j]     = cvtpk(t0 * a0, t1 * a1);
                pk[pr][4 + j] = cvtpk(t0 * acc[2 * half + 1][na][j] + m0 * a0 * a0,
                                      t1 * acc[2 * half + 1][nb][j] + m1 * a1 * a1);
            }
        }
        u16* yrow = Y + (half * 32 + 4 * g) * YP + nbase + 4 * lm;
#pragma unroll
        for (int j = 0; j < 4; ++j) {
            *(uint2*)(yrow + j * YP)        = (uint2){pk[0][j],     pk[1][j]};
            *(uint2*)(yrow + (16 + j) * YP) = (uint2){pk[0][4 + j], pk[1][4 + j]};
        }
    }
    __syncthreads();
}

__global__ __launch_bounds__(256, 4)
void mlp_jet_mfma(const float* __restrict__ x,
                  const float* __restrict__ W0, const float* __restrict__ b0,
                  const float* __restrict__ b1, const float* __restrict__ b2,
                  const float* __restrict__ b3, const float* __restrict__ bo,
                  const u16* __restrict__ Wt,   // 3 x fragment-ordered Wt, + Wob[2][256]
                  float* __restrict__ out, int nB) {
    __shared__ __align__(16) u16 Y[MROWS * YP];
    __shared__ float  part[MROWS][2];

    const int tid = threadIdx.x;
    const int wv  = tid >> 6;            // 0..3
    const int l   = tid & 63;
    const int lm  = l & 15;
    const int lk8 = (l >> 4) * 8;
    const int halfg = nB / (2 * SPBM);   // 1024 blocks per iteration

#pragma unroll 1
    for (int it = 0; it < 2; ++it) {
        const int n0 = (blockIdx.x + it * halfg) * SPBM;

        // ---- layer 0: 4 -> 256, VALU; x loads are wave-uniform broadcasts ----
#pragma unroll
        for (int rep = 0; rep < 2; ++rep) {
            const int idx = tid + 256 * rep;         // 0..511
            const int s   = idx >> 6;                // sample 0..7 (uniform per wave)
            const int cg  = idx & 63;                // 4-col group
            const float4 xv = *(const float4*)(x + (n0 + s) * 4);
            unsigned int pk[2][8];
#pragma unroll
            for (int pr = 0; pr < 2; ++pr) {
                const int c = 4 * cg + 2 * pr;
                const float2 w0 = *(const float2*)(W0 + 0 * HDIM + c);
                const float2 w1 = *(const float2*)(W0 + 1 * HDIM + c);
                const float2 w2 = *(const float2*)(W0 + 2 * HDIM + c);
                const float2 w3 = *(const float2*)(W0 + 3 * HDIM + c);
                const float2 bb = *(const float2*)(b0 + c);
                const float u0 = xv.x*w0.x + xv.y*w1.x + xv.z*w2.x + xv.w*w3.x + bb.x;
                const float u1 = xv.x*w0.y + xv.y*w1.y + xv.z*w2.y + xv.w*w3.y + bb.y;
                const float ty0 = fast_tanh(u0), ty1 = fast_tanh(u1);
                const float t0 = 1.f - ty0 * ty0, t1 = 1.f - ty1 * ty1;
                const float m0 = -2.f * ty0 * t0, m1 = -2.f * ty1 * t1;
                pk[pr][0] = cvtpk(ty0, ty1);                      // ch0: tanh
                pk[pr][1] = cvtpk(t0 * w0.x, t1 * w0.y);          // ch1: t*w0
                pk[pr][2] = cvtpk(t0 * w1.x, t1 * w1.y);          // ch2: t*w1
                pk[pr][3] = cvtpk(t0 * w2.x, t1 * w2.y);          // ch3: t*w2
                pk[pr][4] = cvtpk(t0 * w3.x, t1 * w3.y);          // ch4: t*w3
                pk[pr][5] = cvtpk(m0 * w0.x * w0.x, m1 * w0.y * w0.y); // ch5
                pk[pr][6] = cvtpk(m0 * w1.x * w1.x, m1 * w1.y * w1.y); // ch6
                pk[pr][7] = cvtpk(m0 * w2.x * w2.x, m1 * w2.y * w2.y); // ch7
            }
            // permuted rows: ch0..3 at R.., ch4..7 at R+16..;  R = 32*(s>>2)+4*(s&3)
            u16* yr = Y + (32 * (s >> 2) + 4 * (s & 3)) * YP + 4 * cg;
#pragma unroll
            for (int j = 0; j < 4; ++j) {
                *(uint2*)(yr + j * YP)        = (uint2){pk[0][j],     pk[1][j]};
                *(uint2*)(yr + (16 + j) * YP) = (uint2){pk[0][4 + j], pk[1][4 + j]};
            }
        }
        __syncthreads();

        // ---- 3 hidden layers on the matrix pipe ----
        hidden_layer_mfma(Y, Wt + 0 * 65536, b1, l, wv);
        hidden_layer_mfma(Y, Wt + 1 * 65536, b2, l, wv);
        hidden_layer_mfma(Y, Wt + 2 * 65536, b3, l, wv);

        // ---- output head on MFMA: wave wv takes physical rows wv*16..wv*16+15 ----
        {
            const u16* wob = Wt + 3 * 65536;
            f32x4 h = (f32x4){0.f, 0.f, 0.f, 0.f};
#pragma unroll
            for (int ks = 0; ks < 8; ++ks) {
                const int kk = ks * 32 + lk8;
                const short8 a = *(const short8*)(Y + (wv * 16 + lm) * YP + kk);
                short8 bfr = (short8){0,0,0,0,0,0,0,0};
                if (lm < 2) bfr = *(const short8*)(wob + lm * 256 + kk);
                h = __builtin_amdgcn_mfma_f32_16x16x32_bf16(a, bfr, h, 0, 0, 0);
            }
            if (lm < 2) {
#pragma unroll
                for (int r = 0; r < 4; ++r)
                    part[wv * 16 + (l >> 4) * 4 + r][lm] = h[r];
            }
        }
        __syncthreads();   // head Y-reads done -> next iter may overwrite Y

        if (tid < SPBM) {
            const int s = tid;
            float q0[8], q1[8];
#pragma unroll
            for (int ch = 0; ch < 8; ++ch) {
                const int R = 32 * (s >> 2) + 16 * (ch >> 2) + 4 * (s & 3) + (ch & 3);
                q0[ch] = part[R][0];
                q1[ch] = part[R][1];
            }
            const float c0  = q0[0] + bo[0];
            const float Fi  = q1[0] + bo[1];
            const float cg0 = q0[1], cg1 = q0[2], cg2 = q0[3];
            const float ct  = q0[4];                 // dc/dx_3 (TDIM)
            const float fg0 = q1[1], fg1 = q1[2], fg2 = q1[3];
            const float trHc  = q0[5] + q0[6] + q0[7];
            const float fiLap = q1[5] + q1[6] + q1[7];
            const float jd = -trHc
                             - (cg0 * fg0 + cg1 * fg1 + cg2 * fg2 + c0 * fiLap)
                             + 0.1f * (cg0 + cg1 + cg2);
            const int n = n0 + s;
            out[0 * nB + n]         = c0;
            out[1 * nB + n]         = ct;
            out[2 * nB + 3 * n + 0] = cg0;
            out[2 * nB + 3 * n + 1] = cg1;
            out[2 * nB + 3 * n + 2] = cg2;
            out[5 * nB + n]         = Fi;
            out[6 * nB + 3 * n + 0] = fg0;
            out[6 * nB + 3 * n + 1] = fg1;
            out[6 * nB + 3 * n + 2] = fg2;
            out[9 * nB + n]         = fiLap;
            out[10 * nB + n]        = jd;
        }
        // no extra barrier needed: iter-2 layer-0 Y writes are fenced by the
        // post-head barrier; part[] isn't rewritten until after 6 more barriers.
    }
}

extern "C" void kernel_launch(void* const* d_in, const int* in_sizes, int n_in,
                              void* d_out, int out_size, void* d_ws, size_t ws_size,
                              hipStream_t stream) {
    const float* x  = (const float*)d_in[0];
    const float* W0 = (const float*)d_in[1];
    const float* b0 = (const float*)d_in[2];
    const float* W1 = (const float*)d_in[3];
    const float* b1 = (const float*)d_in[4];
    const float* W2 = (const float*)d_in[5];
    const float* b2 = (const float*)d_in[6];
    const float* W3 = (const float*)d_in[7];
    const float* b3 = (const float*)d_in[8];
    const float* Wo = (const float*)d_in[9];
    const float* bo = (const float*)d_in[10];
    float* out = (float*)d_out;
    u16*   Wt  = (u16*)d_ws;                 // 3*65536 + 512 bf16 ≈ 385 KB

    const int nB = in_sizes[0] / 4;          // 16384

    hipLaunchKernelGGL(prep_w, dim3(97), dim3(256), 0, stream, W1, W2, W3, Wo, Wt);
    hipLaunchKernelGGL(mlp_jet_mfma, dim3(nB / SPBM / 2), dim3(256), 0, stream,
                       x, W0, b0, b1, b2, b3, bo, Wt, out, nB);
}

// Round 9
// 127.268 us; speedup vs baseline: 1.9187x; 1.9187x over previous
//
#include <hip/hip_runtime.h>

#define HDIM  256
#define YP    264              // padded Y row length in bf16 elems
#define SPBM  8                // samples per block
#define MROWS (SPBM * 8)       // 64 jet rows per block

typedef unsigned short u16;
typedef __attribute__((ext_vector_type(8))) short  short8;   // 8 bf16 (4 VGPRs)
typedef __attribute__((ext_vector_type(4))) float  f32x4;    // MFMA acc

// ---------------- Wt fragment layout + column permutation (r5/r6) ---------
// B-fragment storage is lane-contiguous (1KB streaming loads per wave), and
// tile-col -> logical-n mapping is permuted:  tile t, tile-col m holds
// logical n = (t>>2)*64 + 4*m + (t&3).  So lane lm's four nt-accumulators
// are logical cols 4*lm..4*lm+3 -> epilogue writes ds_write_b64 per row.
// Row permutation (r3): physical row R for (sample s, channel c):
//   R = 32*(s>>2) + 16*(c>>2) + 4*(s&3) + (c&3)
// => per C-tile pair lane group g holds all 8 channels of sample 4h+g
// in registers -> per-lane jet epilogue, no shuffles.
// Round 9: r7 body EXACTLY (r8's persistent loop caused a ~400MB scratch
// spill - reverted) + PHASE STAGGER: the 4 co-resident blocks start offset
// by ~1/4 layer period so one block's matrix-saturated K-loop overlaps the
// others' epilogue/barrier phases instead of colliding with their K-loops.
// -------------------------------------------------------------------------

// proper RNE, used once in prepass for weights
__device__ __forceinline__ u16 f2bf_rne(float f) {
    union { float f; unsigned int u; } v; v.f = f;
    unsigned int r = v.u + 0x7fffu + ((v.u >> 16) & 1u);
    return (u16)(r >> 16);
}
// pack two f32 -> bf16x2 in one VALU instr (RNE)
__device__ __forceinline__ unsigned int cvtpk(float a, float b) {
    unsigned int r;
    asm("v_cvt_pk_bf16_f32 %0, %1, %2" : "=v"(r) : "v"(a), "v"(b));
    return r;
}
// tanh(x) = 1 - 2/(e^{2x}+1) on raw v_exp_f32 / v_rcp_f32 (~4 instr, NaN-free)
__device__ __forceinline__ float fast_tanh(float x) {
    const float e = __builtin_amdgcn_exp2f(x * 2.885390081777927f); // e^{2x}
    const float r = __builtin_amdgcn_rcpf(e + 1.f);
    return 1.f - 2.f * r;
}

// ---- prepass: W[k][n] f32 -> fragment-ordered, column-permuted bf16 Wt
// ---- (W1,W2,W3), plus Wo[k][2] -> Wob[2][256] bf16 at ws + 3*65536.
// 97 blocks; block = one (ks, 4 n-tiles) slab: 32 k x 64 n.
__global__ __launch_bounds__(256)
void prep_w(const float* __restrict__ W1, const float* __restrict__ W2,
            const float* __restrict__ W3, const float* __restrict__ Wo,
            u16* __restrict__ ws) {
    const int bid = blockIdx.x;
    const int tid = threadIdx.x;
    if (bid == 96) {
#pragma unroll
        for (int oc = 0; oc < 2; ++oc)
            ws[3 * 65536 + oc * 256 + tid] = f2bf_rne(Wo[tid * 2 + oc]);
        return;
    }
    const int which = bid >> 5;          // 0..2
    const int tile  = bid & 31;          // 8 k-slabs x 4 n-slabs
    const int k0 = (tile & 7) * 32;      // ks = tile & 7
    const int n0 = (tile >> 3) * 64;
    const float* W = (which == 0) ? W1 : ((which == 1) ? W2 : W3);
    __shared__ float T[32][65];
    const int rk = tid >> 4;             // 0..15
    const int rn = (tid & 15) * 4;       // 0..60
#pragma unroll
    for (int rep = 0; rep < 2; ++rep) {
        const float4 v = *(const float4*)(W + (k0 + rep * 16 + rk) * 256 + n0 + rn);
        T[rep * 16 + rk][rn + 0] = v.x;
        T[rep * 16 + rk][rn + 1] = v.y;
        T[rep * 16 + rk][rn + 2] = v.z;
        T[rep * 16 + rk][rn + 3] = v.w;
    }
    __syncthreads();
    // fragment-ordered write: thread -> (t_local = tid>>6, lane = tid&63)
    const int tl = tid >> 6;             // 0..3  (n-tile within slab, = t&3)
    const int ln = tid & 63;             // fragment lane
    const int nn = 4 * (ln & 15) + tl;           // PERMUTED logical n - n0
    const int kb = ((ln >> 4) & 3) * 8;          // k - k0 base
    short8 o;
#pragma unroll
    for (int j = 0; j < 8; ++j)
        o[j] = (short)f2bf_rne(T[kb + j][nn]);
    const int t_glob = (n0 >> 4) + tl;           // 0..15
    *(short8*)(ws + which * 65536 + ((t_glob * 8 + (tile & 7)) * 64 + ln) * 8) = o;
}

// ---- one hidden layer: Y(LDS, 64x256 bf16 jets) @ W(256x256) -> jets, in place ----
// 4 waves: wave wv owns all 64 rows x cols wv*64..+63.  acc[4][4] = 64 regs.
// C/D: col=lane&15, row=(lane>>4)*4+reg.  A: A[m=lane&15][k=8*(lane>>4)+j].
// B-loads lane-contiguous 1KB streams; B cols permuted (see header comment).
__device__ __forceinline__ void hidden_layer_mfma(u16* __restrict__ Y,
                                                  const u16* __restrict__ Wt,
                                                  const float* __restrict__ b,
                                                  int l, int wv) {
    const int lm    = l & 15;
    const int lk8   = (l >> 4) * 8;
    const int nbase = wv * 64;
    // per-lane fragment base: t = wv*4 + nt  ->  elem off = (t*8+ks)*512 + l*8
    const u16* bsrc = Wt + (wv * 4) * 4096 + l * 8;

    f32x4 acc[4][4];
#pragma unroll
    for (int mt = 0; mt < 4; ++mt)
#pragma unroll
        for (int nt = 0; nt < 4; ++nt) acc[mt][nt] = (f32x4){0.f, 0.f, 0.f, 0.f};

#pragma unroll
    for (int ks = 0; ks < 8; ++ks) {
        const int kk = ks * 32 + lk8;
        short8 a[4], bf[4];
#pragma unroll
        for (int mt = 0; mt < 4; ++mt)
            a[mt] = *(const short8*)(Y + (mt * 16 + lm) * YP + kk);
#pragma unroll
        for (int nt = 0; nt < 4; ++nt)
            bf[nt] = *(const short8*)(bsrc + nt * 4096 + ks * 512);
#pragma unroll
        for (int mt = 0; mt < 4; ++mt)
#pragma unroll
            for (int nt = 0; nt < 4; ++nt)
                acc[mt][nt] = __builtin_amdgcn_mfma_f32_16x16x32_bf16(
                    a[mt], bf[nt], acc[mt][nt], 0, 0, 0);
    }

    // bias for logical cols nbase + 4*lm + 0..3  (one float4)
    const float4 b4 = *(const float4*)(b + nbase + 4 * lm);

    __syncthreads();   // all waves done READING Y before anyone overwrites it

    const int g = l >> 4;    // sample-in-group 0..3
#pragma unroll
    for (int half = 0; half < 2; ++half) {      // samples 4*half+g
        // pk[pr][row]: pr = nt-pair (cols 4lm+2pr, +1); rows 0..3 = ch0..3,
        // rows 4..7 = ch4..7.  All indices compile-time -> registers.
        unsigned int pk[2][8];
#pragma unroll
        for (int pr = 0; pr < 2; ++pr) {
            const int na = 2 * pr, nb = 2 * pr + 1;
            const float bba = (pr == 0) ? b4.x : b4.z;
            const float bbb = (pr == 0) ? b4.y : b4.w;
            const float ty0 = fast_tanh(acc[2 * half][na][0] + bba);
            const float ty1 = fast_tanh(acc[2 * half][nb][0] + bbb);
            const float t0 = 1.f - ty0 * ty0, t1 = 1.f - ty1 * ty1;
            const float m0 = -2.f * ty0 * t0, m1 = -2.f * ty1 * t1;
            pk[pr][0] = cvtpk(ty0, ty1);
            pk[pr][4] = cvtpk(t0 * acc[2 * half + 1][na][0],
                              t1 * acc[2 * half + 1][nb][0]);
#pragma unroll
            for (int j = 1; j < 4; ++j) {
                const float a0 = acc[2 * half][na][j];
                const float a1 = acc[2 * half][nb][j];
                pk[pr][j]     = cvtpk(t0 * a0, t1 * a1);
                pk[pr][4 + j] = cvtpk(t0 * acc[2 * half + 1][na][j] + m0 * a0 * a0,
                                      t1 * acc[2 * half + 1][nb][j] + m1 * a1 * a1);
            }
        }
        u16* yrow = Y + (half * 32 + 4 * g) * YP + nbase + 4 * lm;
#pragma unroll
        for (int j = 0; j < 4; ++j) {
            *(uint2*)(yrow + j * YP)        = (uint2){pk[0][j],     pk[1][j]};
            *(uint2*)(yrow + (16 + j) * YP) = (uint2){pk[0][4 + j], pk[1][4 + j]};
        }
    }
    __syncthreads();
}

__global__ __launch_bounds__(256, 4)
void mlp_jet_mfma(const float* __restrict__ x,
                  const float* __restrict__ W0, const float* __restrict__ b0,
                  const float* __restrict__ b1, const float* __restrict__ b2,
                  const float* __restrict__ b3, const float* __restrict__ bo,
                  const u16* __restrict__ Wt,   // 3 x fragment-ordered Wt, + Wob[2][256]
                  float* __restrict__ out, int nB) {
    __shared__ __align__(16) u16 Y[MROWS * YP];
    __shared__ float4 xs4[SPBM];
    __shared__ float  part[MROWS][2];

    const int tid = threadIdx.x;
    const int wv  = tid >> 6;            // 0..3
    const int l   = tid & 63;
    const int lm  = l & 15;
    const int lk8 = (l >> 4) * 8;
    const int n0  = blockIdx.x * SPBM;

    // phase-stagger: desynchronize the 4 co-resident blocks so their
    // matrix-saturated K-loops overlap other blocks' epilogue/barrier phases.
    // Same-CU blocks differ in blockIdx bits >= 8 (8 XCDs x 32 CUs).
    // Each s_sleep(40) ~ 2560 cycles ~ 1/4 of a layer period.
    const int ph = (blockIdx.x >> 8) & 3;
    if (ph & 1) __builtin_amdgcn_s_sleep(40);
    if (ph & 2) { __builtin_amdgcn_s_sleep(40); __builtin_amdgcn_s_sleep(40); }

    // ---- layer 0: 4 -> 256, VALU; thread -> (sample, 4-col group), pair-wise ----
    if (tid < SPBM) xs4[tid] = *(const float4*)(x + (n0 + tid) * 4);
    __syncthreads();
#pragma unroll
    for (int rep = 0; rep < 2; ++rep) {
        const int idx = tid + 256 * rep;         // 0..511
        const int s   = idx >> 6;                // sample 0..7 (uniform per wave)
        const int cg  = idx & 63;                // 4-col group
        const float4 xv = xs4[s];
        unsigned int pk[2][8];
#pragma unroll
        for (int pr = 0; pr < 2; ++pr) {
            const int c = 4 * cg + 2 * pr;
            const float2 w0 = *(const float2*)(W0 + 0 * HDIM + c);
            const float2 w1 = *(const float2*)(W0 + 1 * HDIM + c);
            const float2 w2 = *(const float2*)(W0 + 2 * HDIM + c);
            const float2 w3 = *(const float2*)(W0 + 3 * HDIM + c);
            const float2 bb = *(const float2*)(b0 + c);
            const float u0 = xv.x*w0.x + xv.y*w1.x + xv.z*w2.x + xv.w*w3.x + bb.x;
            const float u1 = xv.x*w0.y + xv.y*w1.y + xv.z*w2.y + xv.w*w3.y + bb.y;
            const float ty0 = fast_tanh(u0), ty1 = fast_tanh(u1);
            const float t0 = 1.f - ty0 * ty0, t1 = 1.f - ty1 * ty1;
            const float m0 = -2.f * ty0 * t0, m1 = -2.f * ty1 * t1;
            pk[pr][0] = cvtpk(ty0, ty1);                      // ch0: tanh
            pk[pr][1] = cvtpk(t0 * w0.x, t1 * w0.y);          // ch1: t*w0
            pk[pr][2] = cvtpk(t0 * w1.x, t1 * w1.y);          // ch2: t*w1
            pk[pr][3] = cvtpk(t0 * w2.x, t1 * w2.y);          // ch3: t*w2
            pk[pr][4] = cvtpk(t0 * w3.x, t1 * w3.y);          // ch4: t*w3
            pk[pr][5] = cvtpk(m0 * w0.x * w0.x, m1 * w0.y * w0.y); // ch5
            pk[pr][6] = cvtpk(m0 * w1.x * w1.x, m1 * w1.y * w1.y); // ch6
            pk[pr][7] = cvtpk(m0 * w2.x * w2.x, m1 * w2.y * w2.y); // ch7
        }
        // permuted rows: ch0..3 at R.., ch4..7 at R+16..;  R = 32*(s>>2)+4*(s&3)
        u16* yr = Y + (32 * (s >> 2) + 4 * (s & 3)) * YP + 4 * cg;
#pragma unroll
        for (int j = 0; j < 4; ++j) {
            *(uint2*)(yr + j * YP)        = (uint2){pk[0][j],     pk[1][j]};
            *(uint2*)(yr + (16 + j) * YP) = (uint2){pk[0][4 + j], pk[1][4 + j]};
        }
    }
    __syncthreads();

    // ---- 3 hidden layers on the matrix pipe ----
    hidden_layer_mfma(Y, Wt + 0 * 65536, b1, l, wv);
    hidden_layer_mfma(Y, Wt + 1 * 65536, b2, l, wv);
    hidden_layer_mfma(Y, Wt + 2 * 65536, b3, l, wv);

    // ---- output head on MFMA: wave wv takes physical rows wv*16..wv*16+15 ----
    {
        const u16* wob = Wt + 3 * 65536;
        f32x4 h = (f32x4){0.f, 0.f, 0.f, 0.f};
#pragma unroll
        for (int ks = 0; ks < 8; ++ks) {
            const int kk = ks * 32 + lk8;
            const short8 a = *(const short8*)(Y + (wv * 16 + lm) * YP + kk);
            short8 bfr = (short8){0,0,0,0,0,0,0,0};
            if (lm < 2) bfr = *(const short8*)(wob + lm * 256 + kk);
            h = __builtin_amdgcn_mfma_f32_16x16x32_bf16(a, bfr, h, 0, 0, 0);
        }
        if (lm < 2) {
#pragma unroll
            for (int r = 0; r < 4; ++r)
                part[wv * 16 + (l >> 4) * 4 + r][lm] = h[r];
        }
    }
    __syncthreads();

    if (tid < SPBM) {
        const int s = tid;
        float q0[8], q1[8];
#pragma unroll
        for (int ch = 0; ch < 8; ++ch) {
            const int R = 32 * (s >> 2) + 16 * (ch >> 2) + 4 * (s & 3) + (ch & 3);
            q0[ch] = part[R][0];
            q1[ch] = part[R][1];
        }
        const float c0  = q0[0] + bo[0];
        const float Fi  = q1[0] + bo[1];
        const float cg0 = q0[1], cg1 = q0[2], cg2 = q0[3];
        const float ct  = q0[4];                 // dc/dx_3 (TDIM)
        const float fg0 = q1[1], fg1 = q1[2], fg2 = q1[3];
        const float trHc  = q0[5] + q0[6] + q0[7];
        const float fiLap = q1[5] + q1[6] + q1[7];
        const float jd = -trHc
                         - (cg0 * fg0 + cg1 * fg1 + cg2 * fg2 + c0 * fiLap)
                         + 0.1f * (cg0 + cg1 + cg2);
        const int n = n0 + s;
        out[0 * nB + n]         = c0;
        out[1 * nB + n]         = ct;
        out[2 * nB + 3 * n + 0] = cg0;
        out[2 * nB + 3 * n + 1] = cg1;
        out[2 * nB + 3 * n + 2] = cg2;
        out[5 * nB + n]         = Fi;
        out[6 * nB + 3 * n + 0] = fg0;
        out[6 * nB + 3 * n + 1] = fg1;
        out[6 * nB + 3 * n + 2] = fg2;
        out[9 * nB + n]         = fiLap;
        out[10 * nB + n]        = jd;
    }
}

extern "C" void kernel_launch(void* const* d_in, const int* in_sizes, int n_in,
                              void* d_out, int out_size, void* d_ws, size_t ws_size,
                              hipStream_t stream) {
    const float* x  = (const float*)d_in[0];
    const float* W0 = (const float*)d_in[1];
    const float* b0 = (const float*)d_in[2];
    const float* W1 = (const float*)d_in[3];
    const float* b1 = (const float*)d_in[4];
    const float* W2 = (const float*)d_in[5];
    const float* b2 = (const float*)d_in[6];
    const float* W3 = (const float*)d_in[7];
    const float* b3 = (const float*)d_in[8];
    const float* Wo = (const float*)d_in[9];
    const float* bo = (const float*)d_in[10];
    float* out = (float*)d_out;
    u16*   Wt  = (u16*)d_ws;                 // 3*65536 + 512 bf16 ≈ 385 KB

    const int nB = in_sizes[0] / 4;          // 16384

    hipLaunchKernelGGL(prep_w, dim3(97), dim3(256), 0, stream, W1, W2, W3, Wo, Wt);
    hipLaunchKernelGGL(mlp_jet_mfma, dim3(nB / SPBM), dim3(256), 0, stream,
                       x, W0, b0, b1, b2, b3, bo, Wt, out, nB);
}

// Round 10
// 125.084 us; speedup vs baseline: 1.9522x; 1.0175x over previous
//
#include <hip/hip_runtime.h>

#define HDIM  256
#define YP    264              // padded Y row length in bf16 elems
#define SPBM  8                // samples per block
#define MROWS (SPBM * 8)       // 64 jet rows per block

typedef unsigned short u16;
typedef __attribute__((ext_vector_type(8))) short  short8;   // 8 bf16 (4 VGPRs)
typedef __attribute__((ext_vector_type(4))) float  f32x4;    // MFMA acc

// ---------------- Wt fragment layout + column permutation (r5/r6) ---------
// B-fragment storage is lane-contiguous (1KB streaming loads per wave), and
// tile-col -> logical-n mapping is permuted:  tile t, tile-col m holds
// logical n = (t>>2)*64 + 4*m + (t&3).  So lane lm's four nt-accumulators
// are logical cols 4*lm..4*lm+3 -> epilogue writes ds_write_b64 per row.
// Row permutation (r3): physical row R for (sample s, channel c):
//   R = 32*(s>>2) + 16*(c>>2) + 4*(s&3) + (c&3)
// => per C-tile pair lane group g holds all 8 channels of sample 4h+g
// in registers -> per-lane jet epilogue, no shuffles.
// Round 10: main kernel = r7 EXACTLY (stagger removed: r9 falsified the
// phase-collision theory, cost ~4us).  prep_w rewritten as barrier-free
// streaming gather (no LDS): probes whether the ~67us of non-mlp time is
// prep-bound or harness-fixed.
// -------------------------------------------------------------------------

// proper RNE, used once in prepass for weights
__device__ __forceinline__ u16 f2bf_rne(float f) {
    union { float f; unsigned int u; } v; v.f = f;
    unsigned int r = v.u + 0x7fffu + ((v.u >> 16) & 1u);
    return (u16)(r >> 16);
}
// pack two f32 -> bf16x2 in one VALU instr (RNE)
__device__ __forceinline__ unsigned int cvtpk(float a, float b) {
    unsigned int r;
    asm("v_cvt_pk_bf16_f32 %0, %1, %2" : "=v"(r) : "v"(a), "v"(b));
    return r;
}
// tanh(x) = 1 - 2/(e^{2x}+1) on raw v_exp_f32 / v_rcp_f32 (~4 instr, NaN-free)
__device__ __forceinline__ float fast_tanh(float x) {
    const float e = __builtin_amdgcn_exp2f(x * 2.885390081777927f); // e^{2x}
    const float r = __builtin_amdgcn_rcpf(e + 1.f);
    return 1.f - 2.f * r;
}

// ---- prepass (streaming, no LDS, no barriers): W[k][n] f32 ->
// ---- fragment-ordered, column-permuted bf16 Wt (W1,W2,W3),
// ---- plus Wo[k][2] -> Wob[2][256] bf16 at ws + 3*65536.
// 97 blocks: 3 x 32 work blocks (one short8 per thread) + 1 for Wo.
// Thread -> flat frag index f = ((t*8+ks)*64+l); decode t,ks,l; gather the
// 8 source f32 (L2-resident; 16-lane group spans 256 contiguous bytes).
__global__ __launch_bounds__(256)
void prep_w(const float* __restrict__ W1, const float* __restrict__ W2,
            const float* __restrict__ W3, const float* __restrict__ Wo,
            u16* __restrict__ ws) {
    const int bid = blockIdx.x;
    const int tid = threadIdx.x;
    if (bid == 96) {
#pragma unroll
        for (int oc = 0; oc < 2; ++oc)
            ws[3 * 65536 + oc * 256 + tid] = f2bf_rne(Wo[tid * 2 + oc]);
        return;
    }
    const int which = bid >> 5;                 // 0..2
    const int f = (bid & 31) * 256 + tid;       // 0..8191 flat short8 index
    const int l  = f & 63;                      // fragment lane
    const int ks = (f >> 6) & 7;                // k-slab
    const int t  = f >> 9;                      // n-tile 0..15
    // permuted logical n and k base (must match hidden_layer_mfma's mapping)
    const int n  = (t >> 2) * 64 + 4 * (l & 15) + (t & 3);
    const int k0 = ks * 32 + ((l >> 4) & 3) * 8;
    const float* W = (which == 0) ? W1 : ((which == 1) ? W2 : W3);
    short8 o;
#pragma unroll
    for (int j = 0; j < 8; ++j)
        o[j] = (short)f2bf_rne(W[(k0 + j) * 256 + n]);
    *(short8*)(ws + which * 65536 + f * 8) = o;
}

// ---- one hidden layer: Y(LDS, 64x256 bf16 jets) @ W(256x256) -> jets, in place ----
// 4 waves: wave wv owns all 64 rows x cols wv*64..+63.  acc[4][4] = 64 regs.
// C/D: col=lane&15, row=(lane>>4)*4+reg.  A: A[m=lane&15][k=8*(lane>>4)+j].
// B-loads lane-contiguous 1KB streams; B cols permuted (see header comment).
__device__ __forceinline__ void hidden_layer_mfma(u16* __restrict__ Y,
                                                  const u16* __restrict__ Wt,
                                                  const float* __restrict__ b,
                                                  int l, int wv) {
    const int lm    = l & 15;
    const int lk8   = (l >> 4) * 8;
    const int nbase = wv * 64;
    // per-lane fragment base: t = wv*4 + nt  ->  elem off = (t*8+ks)*512 + l*8
    const u16* bsrc = Wt + (wv * 4) * 4096 + l * 8;

    f32x4 acc[4][4];
#pragma unroll
    for (int mt = 0; mt < 4; ++mt)
#pragma unroll
        for (int nt = 0; nt < 4; ++nt) acc[mt][nt] = (f32x4){0.f, 0.f, 0.f, 0.f};

#pragma unroll
    for (int ks = 0; ks < 8; ++ks) {
        const int kk = ks * 32 + lk8;
        short8 a[4], bf[4];
#pragma unroll
        for (int mt = 0; mt < 4; ++mt)
            a[mt] = *(const short8*)(Y + (mt * 16 + lm) * YP + kk);
#pragma unroll
        for (int nt = 0; nt < 4; ++nt)
            bf[nt] = *(const short8*)(bsrc + nt * 4096 + ks * 512);
#pragma unroll
        for (int mt = 0; mt < 4; ++mt)
#pragma unroll
            for (int nt = 0; nt < 4; ++nt)
                acc[mt][nt] = __builtin_amdgcn_mfma_f32_16x16x32_bf16(
                    a[mt], bf[nt], acc[mt][nt], 0, 0, 0);
    }

    // bias for logical cols nbase + 4*lm + 0..3  (one float4)
    const float4 b4 = *(const float4*)(b + nbase + 4 * lm);

    __syncthreads();   // all waves done READING Y before anyone overwrites it

    const int g = l >> 4;    // sample-in-group 0..3
#pragma unroll
    for (int half = 0; half < 2; ++half) {      // samples 4*half+g
        // pk[pr][row]: pr = nt-pair (cols 4lm+2pr, +1); rows 0..3 = ch0..3,
        // rows 4..7 = ch4..7.  All indices compile-time -> registers.
        unsigned int pk[2][8];
#pragma unroll
        for (int pr = 0; pr < 2; ++pr) {
            const int na = 2 * pr, nb = 2 * pr + 1;
            const float bba = (pr == 0) ? b4.x : b4.z;
            const float bbb = (pr == 0) ? b4.y : b4.w;
            const float ty0 = fast_tanh(acc[2 * half][na][0] + bba);
            const float ty1 = fast_tanh(acc[2 * half][nb][0] + bbb);
            const float t0 = 1.f - ty0 * ty0, t1 = 1.f - ty1 * ty1;
            const float m0 = -2.f * ty0 * t0, m1 = -2.f * ty1 * t1;
            pk[pr][0] = cvtpk(ty0, ty1);
            pk[pr][4] = cvtpk(t0 * acc[2 * half + 1][na][0],
                              t1 * acc[2 * half + 1][nb][0]);
#pragma unroll
            for (int j = 1; j < 4; ++j) {
                const float a0 = acc[2 * half][na][j];
                const float a1 = acc[2 * half][nb][j];
                pk[pr][j]     = cvtpk(t0 * a0, t1 * a1);
                pk[pr][4 + j] = cvtpk(t0 * acc[2 * half + 1][na][j] + m0 * a0 * a0,
                                      t1 * acc[2 * half + 1][nb][j] + m1 * a1 * a1);
            }
        }
        u16* yrow = Y + (half * 32 + 4 * g) * YP + nbase + 4 * lm;
#pragma unroll
        for (int j = 0; j < 4; ++j) {
            *(uint2*)(yrow + j * YP)        = (uint2){pk[0][j],     pk[1][j]};
            *(uint2*)(yrow + (16 + j) * YP) = (uint2){pk[0][4 + j], pk[1][4 + j]};
        }
    }
    __syncthreads();
}

__global__ __launch_bounds__(256, 4)
void mlp_jet_mfma(const float* __restrict__ x,
                  const float* __restrict__ W0, const float* __restrict__ b0,
                  const float* __restrict__ b1, const float* __restrict__ b2,
                  const float* __restrict__ b3, const float* __restrict__ bo,
                  const u16* __restrict__ Wt,   // 3 x fragment-ordered Wt, + Wob[2][256]
                  float* __restrict__ out, int nB) {
    __shared__ __align__(16) u16 Y[MROWS * YP];
    __shared__ float4 xs4[SPBM];
    __shared__ float  part[MROWS][2];

    const int tid = threadIdx.x;
    const int wv  = tid >> 6;            // 0..3
    const int l   = tid & 63;
    const int lm  = l & 15;
    const int lk8 = (l >> 4) * 8;
    const int n0  = blockIdx.x * SPBM;

    // ---- layer 0: 4 -> 256, VALU; thread -> (sample, 4-col group), pair-wise ----
    if (tid < SPBM) xs4[tid] = *(const float4*)(x + (n0 + tid) * 4);
    __syncthreads();
#pragma unroll
    for (int rep = 0; rep < 2; ++rep) {
        const int idx = tid + 256 * rep;         // 0..511
        const int s   = idx >> 6;                // sample 0..7 (uniform per wave)
        const int cg  = idx & 63;                // 4-col group
        const float4 xv = xs4[s];
        unsigned int pk[2][8];
#pragma unroll
        for (int pr = 0; pr < 2; ++pr) {
            const int c = 4 * cg + 2 * pr;
            const float2 w0 = *(const float2*)(W0 + 0 * HDIM + c);
            const float2 w1 = *(const float2*)(W0 + 1 * HDIM + c);
            const float2 w2 = *(const float2*)(W0 + 2 * HDIM + c);
            const float2 w3 = *(const float2*)(W0 + 3 * HDIM + c);
            const float2 bb = *(const float2*)(b0 + c);
            const float u0 = xv.x*w0.x + xv.y*w1.x + xv.z*w2.x + xv.w*w3.x + bb.x;
            const float u1 = xv.x*w0.y + xv.y*w1.y + xv.z*w2.y + xv.w*w3.y + bb.y;
            const float ty0 = fast_tanh(u0), ty1 = fast_tanh(u1);
            const float t0 = 1.f - ty0 * ty0, t1 = 1.f - ty1 * ty1;
            const float m0 = -2.f * ty0 * t0, m1 = -2.f * ty1 * t1;
            pk[pr][0] = cvtpk(ty0, ty1);                      // ch0: tanh
            pk[pr][1] = cvtpk(t0 * w0.x, t1 * w0.y);          // ch1: t*w0
            pk[pr][2] = cvtpk(t0 * w1.x, t1 * w1.y);          // ch2: t*w1
            pk[pr][3] = cvtpk(t0 * w2.x, t1 * w2.y);          // ch3: t*w2
            pk[pr][4] = cvtpk(t0 * w3.x, t1 * w3.y);          // ch4: t*w3
            pk[pr][5] = cvtpk(m0 * w0.x * w0.x, m1 * w0.y * w0.y); // ch5
            pk[pr][6] = cvtpk(m0 * w1.x * w1.x, m1 * w1.y * w1.y); // ch6
            pk[pr][7] = cvtpk(m0 * w2.x * w2.x, m1 * w2.y * w2.y); // ch7
        }
        // permuted rows: ch0..3 at R.., ch4..7 at R+16..;  R = 32*(s>>2)+4*(s&3)
        u16* yr = Y + (32 * (s >> 2) + 4 * (s & 3)) * YP + 4 * cg;
#pragma unroll
        for (int j = 0; j < 4; ++j) {
            *(uint2*)(yr + j * YP)        = (uint2){pk[0][j],     pk[1][j]};
            *(uint2*)(yr + (16 + j) * YP) = (uint2){pk[0][4 + j], pk[1][4 + j]};
        }
    }
    __syncthreads();

    // ---- 3 hidden layers on the matrix pipe ----
    hidden_layer_mfma(Y, Wt + 0 * 65536, b1, l, wv);
    hidden_layer_mfma(Y, Wt + 1 * 65536, b2, l, wv);
    hidden_layer_mfma(Y, Wt + 2 * 65536, b3, l, wv);

    // ---- output head on MFMA: wave wv takes physical rows wv*16..wv*16+15 ----
    {
        const u16* wob = Wt + 3 * 65536;
        f32x4 h = (f32x4){0.f, 0.f, 0.f, 0.f};
#pragma unroll
        for (int ks = 0; ks < 8; ++ks) {
            const int kk = ks * 32 + lk8;
            const short8 a = *(const short8*)(Y + (wv * 16 + lm) * YP + kk);
            short8 bfr = (short8){0,0,0,0,0,0,0,0};
            if (lm < 2) bfr = *(const short8*)(wob + lm * 256 + kk);
            h = __builtin_amdgcn_mfma_f32_16x16x32_bf16(a, bfr, h, 0, 0, 0);
        }
        if (lm < 2) {
#pragma unroll
            for (int r = 0; r < 4; ++r)
                part[wv * 16 + (l >> 4) * 4 + r][lm] = h[r];
        }
    }
    __syncthreads();

    if (tid < SPBM) {
        const int s = tid;
        float q0[8], q1[8];
#pragma unroll
        for (int ch = 0; ch < 8; ++ch) {
            const int R = 32 * (s >> 2) + 16 * (ch >> 2) + 4 * (s & 3) + (ch & 3);
            q0[ch] = part[R][0];
            q1[ch] = part[R][1];
        }
        const float c0  = q0[0] + bo[0];
        const float Fi  = q1[0] + bo[1];
        const float cg0 = q0[1], cg1 = q0[2], cg2 = q0[3];
        const float ct  = q0[4];                 // dc/dx_3 (TDIM)
        const float fg0 = q1[1], fg1 = q1[2], fg2 = q1[3];
        const float trHc  = q0[5] + q0[6] + q0[7];
        const float fiLap = q1[5] + q1[6] + q1[7];
        const float jd = -trHc
                         - (cg0 * fg0 + cg1 * fg1 + cg2 * fg2 + c0 * fiLap)
                         + 0.1f * (cg0 + cg1 + cg2);
        const int n = n0 + s;
        out[0 * nB + n]         = c0;
        out[1 * nB + n]         = ct;
        out[2 * nB + 3 * n + 0] = cg0;
        out[2 * nB + 3 * n + 1] = cg1;
        out[2 * nB + 3 * n + 2] = cg2;
        out[5 * nB + n]         = Fi;
        out[6 * nB + 3 * n + 0] = fg0;
        out[6 * nB + 3 * n + 1] = fg1;
        out[6 * nB + 3 * n + 2] = fg2;
        out[9 * nB + n]         = fiLap;
        out[10 * nB + n]        = jd;
    }
}

extern "C" void kernel_launch(void* const* d_in, const int* in_sizes, int n_in,
                              void* d_out, int out_size, void* d_ws, size_t ws_size,
                              hipStream_t stream) {
    const float* x  = (const float*)d_in[0];
    const float* W0 = (const float*)d_in[1];
    const float* b0 = (const float*)d_in[2];
    const float* W1 = (const float*)d_in[3];
    const float* b1 = (const float*)d_in[4];
    const float* W2 = (const float*)d_in[5];
    const float* b2 = (const float*)d_in[6];
    const float* W3 = (const float*)d_in[7];
    const float* b3 = (const float*)d_in[8];
    const float* Wo = (const float*)d_in[9];
    const float* bo = (const float*)d_in[10];
    float* out = (float*)d_out;
    u16*   Wt  = (u16*)d_ws;                 // 3*65536 + 512 bf16 ≈ 385 KB

    const int nB = in_sizes[0] / 4;          // 16384

    hipLaunchKernelGGL(prep_w, dim3(97), dim3(256), 0, stream, W1, W2, W3, Wo, Wt);
    hipLaunchKernelGGL(mlp_jet_mfma, dim3(nB / SPBM), dim3(256), 0, stream,
                       x, W0, b0, b1, b2, b3, bo, Wt, out, nB);
}